// Round 11
// baseline (1084.382 us; speedup 1.0000x reference)
//
#include <hip/hip_runtime.h>
#include <stdint.h>

// GRU decoder: 65536 rows, H=256, T=12, D_OUT=64.
// R11: R10 register-state design, reorganized as 2 blocks/CU to break
// barrier lockstep. 256 thr/block (4 waves x 32 rows = 128 rows), grid 512
// = 2 blocks/CU; LDS 68.9KB (ring-2 x 32KB panels + biases) so both fit.
// State h/rh/hn in registers as B-frags (lane=row); weights stream via
// global_load_lds ring-2, 1-ahead prefetch, vmcnt(0)+barrier per phase.

#define TSTEPS 12
#define AS3 __attribute__((address_space(3)))

typedef _Float16 f16x8 __attribute__((ext_vector_type(8)));
typedef _Float16 f16x2 __attribute__((ext_vector_type(2)));
typedef float    f32x16 __attribute__((ext_vector_type(16)));
typedef float    f32x4  __attribute__((ext_vector_type(4)));
typedef uint32_t u32x4  __attribute__((ext_vector_type(4)));

typedef AS3 uint8_t       u8l;
typedef const AS3 uint8_t cu8l;

// ws: f16 weights (panels of 64 rows x 256 k = 32KB):
//   0-3 gate-r(folded), 4-7 gate-z(folded), 8-11 W1, 12-15 W2, 16 Wp
// then f32 bias block in C-layout e-pattern order.
#define WG_E (512*256)
#define W1_E (256*256)
#define WS_W_F16 (WG_E + 2*W1_E + 64*256)
#define BIAS_F32 832
#define WS_BYTES (WS_W_F16*2 + BIAS_F32*4)

__global__ void prep_weights(const float* __restrict__ gw,
                             const float* __restrict__ ow,
                             const float* __restrict__ pw,
                             const float* __restrict__ gb,
                             const float* __restrict__ ob,
                             const float* __restrict__ pb,
                             _Float16* __restrict__ ws)
{
    int idx = blockIdx.x*256 + threadIdx.x;
    if (idx < WG_E) {                           // folded gates
        int j = idx >> 8, k = idx & 255;
        ws[idx] = (_Float16)(gw[j*512 + k] + gw[j*512 + 256 + k]);
    } else if (idx < WG_E + W1_E) {             // W1 = out_w[:, :256]
        int i = idx - WG_E; int r = i >> 8, c = i & 255;
        ws[idx] = (_Float16)ow[r*512 + c];
    } else if (idx < WG_E + 2*W1_E) {           // W2 = out_w[:, 256:]
        int i = idx - WG_E - W1_E; int r = i >> 8, c = i & 255;
        ws[idx] = (_Float16)ow[r*512 + 256 + c];
    } else if (idx < WS_W_F16) {                // Wp
        ws[idx] = (_Float16)pw[idx - WG_E - 2*W1_E];
    } else if (idx < WS_W_F16 + BIAS_F32) {     // expanded biases (f32)
        int b = idx - WS_W_F16;
        float* bd = (float*)(ws + WS_W_F16);
        if (b < 768) {
            int type = b >> 8, r = b & 255;
            int c = r >> 6, n = (r >> 5) & 1, kg = (r >> 4) & 1, e = r & 15;
            int col = 64*c + 32*n + 4*kg + (e & 3) + 8*(e >> 2);
            bd[b] = (type == 0) ? gb[col] : (type == 1) ? gb[256 + col] : ob[col];
        } else {
            int i = b - 768;
            int n = (i >> 5) & 1, kg = (i >> 4) & 1, e = i & 15;
            bd[b] = pb[32*n + 4*kg + (e & 3) + 8*(e >> 2)];
        }
    }
}

__device__ __forceinline__ float sigm(float x)  { return 1.0f/(1.0f+__expf(-x)); }
__device__ __forceinline__ float tanh_(float x) { return 1.0f - 2.0f/(1.0f+__expf(2.0f*x)); }

// stage one 32KB panel (4 waves x 8 gll16). LDS dest linear; global source
// pre-applies the inverse chunk-XOR layout permutation.
__device__ __forceinline__ void stage(const uint8_t* __restrict__ Wp,
                                      u8l* slot, int w, int lane)
{
    #pragma unroll
    for (int i = 0; i < 8; ++i) {
        int d  = w*8192 + i*1024;
        int dl = d + lane*16;
        int chunk = (dl>>7)&31, sl = (dl>>4)&7;
        int row = ((dl>>12)<<3) | (sl ^ (chunk&7));
        int s   = row*512 + chunk*16;
        __builtin_amdgcn_global_load_lds(
            (const __attribute__((address_space(1))) uint32_t*)(Wp + s),
            (AS3 uint32_t*)(slot + d), 16, 0, 0);
    }
}

// load f32x16 bias (broadcast within kg-half)
__device__ __forceinline__ f32x16 ldbias(cu8l* p) {
    f32x16 r;
    #pragma unroll
    for (int j = 0; j < 4; ++j) {
        f32x4 t = *(const AS3 f32x4*)(p + j*16);
        r[j*4+0]=t[0]; r[j*4+1]=t[1]; r[j*4+2]=t[2]; r[j*4+3]=t[3];
    }
    return r;
}

// pack 4 f16x2 words (C-layout e-pattern, 8 outcols) -> B-frag f16x8.
__device__ __forceinline__ f16x8 pk8(uint32_t w01, uint32_t w23,
                                     uint32_t w45, uint32_t w67, int kg) {
    uint32_t s01 = __shfl_xor(w01, 32, 64);
    uint32_t s23 = __shfl_xor(w23, 32, 64);
    uint32_t s45 = __shfl_xor(w45, 32, 64);
    uint32_t s67 = __shfl_xor(w67, 32, 64);
    u32x4 u = { kg ? s45 : w01, kg ? s67 : w23,
                kg ? w45 : s01, kg ? w67 : s23 };
    return __builtin_bit_cast(f16x8, u);
}
__device__ __forceinline__ f16x8 pkS(const f32x16& a, int off, int kg) {
    f16x2 a01 = {(_Float16)sigm(a[off+0]), (_Float16)sigm(a[off+1])};
    f16x2 a23 = {(_Float16)sigm(a[off+2]), (_Float16)sigm(a[off+3])};
    f16x2 a45 = {(_Float16)sigm(a[off+4]), (_Float16)sigm(a[off+5])};
    f16x2 a67 = {(_Float16)sigm(a[off+6]), (_Float16)sigm(a[off+7])};
    return pk8(__builtin_bit_cast(uint32_t, a01), __builtin_bit_cast(uint32_t, a23),
               __builtin_bit_cast(uint32_t, a45), __builtin_bit_cast(uint32_t, a67), kg);
}
__device__ __forceinline__ f16x8 pkT(const f32x16& a, int off, int kg) {
    f16x2 a01 = {(_Float16)tanh_(a[off+0]), (_Float16)tanh_(a[off+1])};
    f16x2 a23 = {(_Float16)tanh_(a[off+2]), (_Float16)tanh_(a[off+3])};
    f16x2 a45 = {(_Float16)tanh_(a[off+4]), (_Float16)tanh_(a[off+5])};
    f16x2 a67 = {(_Float16)tanh_(a[off+6]), (_Float16)tanh_(a[off+7])};
    return pk8(__builtin_bit_cast(uint32_t, a01), __builtin_bit_cast(uint32_t, a23),
               __builtin_bit_cast(uint32_t, a45), __builtin_bit_cast(uint32_t, a67), kg);
}

// one panel GEMM: acc_n += W[32n+(l&31), k] * B (B = reg-resident h or rh)
__device__ __forceinline__ void gemm2(cu8l* pan, int R0, int R1,
                                      const f16x8* B, f32x16& a0, f32x16& a1) {
    __builtin_amdgcn_s_setprio(1);
    #pragma unroll
    for (int ks = 0; ks < 16; ++ks) {
        const int xk = ((2*ks)&7) << 4;
        f16x8 w0 = *(const AS3 f16x8*)(pan + ((R0 ^ xk) + ks*256));
        f16x8 w1 = *(const AS3 f16x8*)(pan + ((R1 ^ xk) + ks*256));
        a0 = __builtin_amdgcn_mfma_f32_32x32x16_f16(w0, B[ks], a0, 0, 0, 0);
        a1 = __builtin_amdgcn_mfma_f32_32x32x16_f16(w1, B[ks], a1, 0, 0, 0);
    }
    __builtin_amdgcn_s_setprio(0);
}

// phase: wait my prefetched panel -> barrier (all waves' loads done, prior
// reads retired) -> prefetch next panel into other slot -> compute current.
#define PHASE(SP_NEXT, ...) do {                                            \
    asm volatile("s_waitcnt vmcnt(0)" ::: "memory");                        \
    asm volatile("s_waitcnt lgkmcnt(0)" ::: "memory");                      \
    __builtin_amdgcn_s_barrier();                                           \
    asm volatile("" ::: "memory");                                          \
    stage(W + (SP_NEXT)*32768, WbL + (sC^1)*32768, w, lane);                \
    { cu8l* pan = WbL + sC*32768; __VA_ARGS__; }                            \
    sC ^= 1;                                                                \
} while (0)

__global__ __launch_bounds__(256, 2)
void gru_dec(const float* __restrict__ h_in, const _Float16* __restrict__ Wf,
             float* __restrict__ out)
{
    __shared__ __align__(16) uint8_t lds_[68864];
    u8l* ldsb = (u8l*)lds_;
    u8l* WbL  = ldsb;                     // 2 x 32KB panel ring
    u8l* biasL = ldsb + 65536;            // 3.3KB expanded biases
    const uint8_t* W = (const uint8_t*)Wf;

    const int tid  = threadIdx.x;
    const int lane = tid & 63;
    const int w    = tid >> 6;            // wave 0..3, owns 32 rows
    const int bl31 = lane & 31;
    const int kg   = lane >> 5;
    const int l7   = lane & 7;
    const size_t rowg = (size_t)blockIdx.x*128 + w*32 + bl31;

    // ---- h -> registers as B-frags: h[ks] = h[rowg, 16ks+8kg+0..7] ----
    f16x8 h[16], rh[16], hn[16];
    {
        const float* hs = h_in + rowg*256 + kg*8;
        #pragma unroll
        for (int ks = 0; ks < 16; ++ks) {
            f32x4 x = *(const f32x4*)(hs + ks*16);
            f32x4 y = *(const f32x4*)(hs + ks*16 + 4);
            f16x8 v = {(_Float16)x[0],(_Float16)x[1],(_Float16)x[2],(_Float16)x[3],
                       (_Float16)y[0],(_Float16)y[1],(_Float16)y[2],(_Float16)y[3]};
            h[ks] = v;
        }
    }
    // ---- biases ws -> LDS ----
    {
        const float* bsrc = (const float*)(Wf + WS_W_F16);
        for (int i = tid; i < BIAS_F32; i += 256)
            *(AS3 float*)(biasL + i*4) = bsrc[i];
    }
    __syncthreads();                      // drains h loads + bias writes

    // per-lane panel-read bases (chunk-XOR layout)
    const int R0 = ((bl31 >> 3))*4096 + kg*128 + ((l7 ^ kg) << 4);
    const int R1 = R0 + 4*4096;
    cu8l* bK = biasL + kg*64;

    stage(W + 0*32768, WbL, w, lane);     // prologue: panel r0 -> slot 0
    int sC = 0;

    for (int t = 0; t < TSTEPS; ++t) {
        f32x16 o0, o1;
        f16x8 zb[4];

        // ---- r gates (panels 0..3): rh[4c+i] = sigm(h@Wr_c + rb) * h ----
#define RPH(SP_NXT, C)                                                        \
        PHASE(SP_NXT, {                                                       \
            f32x16 a0 = ldbias(bK + (C)*256);                                 \
            f32x16 a1 = ldbias(bK + (C)*256 + 128);                           \
            gemm2(pan, R0, R1, h, a0, a1);                                    \
            rh[4*(C)+0] = pkS(a0, 0, kg)*h[4*(C)+0];                          \
            rh[4*(C)+1] = pkS(a0, 8, kg)*h[4*(C)+1];                          \
            rh[4*(C)+2] = pkS(a1, 0, kg)*h[4*(C)+2];                          \
            rh[4*(C)+3] = pkS(a1, 8, kg)*h[4*(C)+3]; })
        RPH(1, 0); RPH(2, 1); RPH(3, 2); RPH(4, 3);
#undef RPH

        // ---- per chunk c: z -> W1 -> W2+combine ----
#define ZPH(SP_NXT, C)                                                        \
        PHASE(SP_NXT, {                                                       \
            f32x16 a0 = ldbias(bK + 1024 + (C)*256);                          \
            f32x16 a1 = ldbias(bK + 1024 + (C)*256 + 128);                    \
            gemm2(pan, R0, R1, h, a0, a1);                                    \
            zb[0] = pkS(a0, 0, kg); zb[1] = pkS(a0, 8, kg);                   \
            zb[2] = pkS(a1, 0, kg); zb[3] = pkS(a1, 8, kg); })
#define W1PH(SP_NXT, C)                                                       \
        PHASE(SP_NXT, {                                                       \
            o0 = ldbias(bK + 2048 + (C)*256);                                 \
            o1 = ldbias(bK + 2048 + (C)*256 + 128);                           \
            gemm2(pan, R0, R1, h, o0, o1); })
#define W2PH(SP_NXT, C)                                                       \
        PHASE(SP_NXT, {                                                       \
            gemm2(pan, R0, R1, rh, o0, o1);                                   \
            f16x8 u0 = pkT(o0, 0, kg), u1 = pkT(o0, 8, kg);                   \
            f16x8 u2 = pkT(o1, 0, kg), u3 = pkT(o1, 8, kg);                   \
            hn[4*(C)+0] = u0 + zb[0]*(h[4*(C)+0] - u0);                       \
            hn[4*(C)+1] = u1 + zb[1]*(h[4*(C)+1] - u1);                       \
            hn[4*(C)+2] = u2 + zb[2]*(h[4*(C)+2] - u2);                       \
            hn[4*(C)+3] = u3 + zb[3]*(h[4*(C)+3] - u3); })

        // compute order (panel): z0=4 W1_0=8 W2_0=12, z1=5 W1_1=9 W2_1=13,
        //                        z2=6 W1_2=10 W2_2=14, z3=7 W1_3=11 W2_3=15
        ZPH(8, 0);  W1PH(12, 0); W2PH(5,  0);
        ZPH(9, 1);  W1PH(13, 1); W2PH(6,  1);
        ZPH(10, 2); W1PH(14, 2); W2PH(7,  2);
        ZPH(11, 3); W1PH(15, 3); W2PH(16, 3);
#undef ZPH
#undef W1PH
#undef W2PH

        // h <- h_new
        #pragma unroll
        for (int i = 0; i < 16; ++i) h[i] = hn[i];

        // ---- proj (panel 16): out_t = h_new @ Wp^T + pb; prefetch next r0 ----
        PHASE(0, {
            f32x16 a0 = ldbias(bK + 3072);
            f32x16 a1 = ldbias(bK + 3072 + 128);
            gemm2(pan, R0, R1, h, a0, a1);
            float* op = out + (rowg*TSTEPS + t)*64 + 4*kg;
            _Pragma("unroll")
            for (int j = 0; j < 4; ++j) {
                f32x4 v0 = {a0[4*j], a0[4*j+1], a0[4*j+2], a0[4*j+3]};
                f32x4 v1 = {a1[4*j], a1[4*j+1], a1[4*j+2], a1[4*j+3]};
                *(f32x4*)(op + 8*j)      = v0;
                *(f32x4*)(op + 32 + 8*j) = v1;
            }
        });
    }
}

extern "C" void kernel_launch(void* const* d_in, const int* in_sizes, int n_in,
                              void* d_out, int out_size, void* d_ws, size_t ws_size,
                              hipStream_t stream) {
    // inputs: 0:x(=12) 1:h 2:gate_w 3:gate_b 4:out_w 5:out_b 6:proj_w 7:proj_b
    const float* h  = (const float*)d_in[1];
    const float* gw = (const float*)d_in[2];
    const float* gb = (const float*)d_in[3];
    const float* ow = (const float*)d_in[4];
    const float* ob = (const float*)d_in[5];
    const float* pw = (const float*)d_in[6];
    const float* pb = (const float*)d_in[7];
    if (ws_size < (size_t)WS_BYTES) return;
    _Float16* ws = (_Float16*)d_ws;

    hipLaunchKernelGGL(prep_weights, dim3((WS_W_F16 + BIAS_F32 + 255)/256), dim3(256),
                       0, stream, gw, ow, pw, gb, ob, pb, ws);
    hipLaunchKernelGGL(gru_dec, dim3(65536/128), dim3(256), 0, stream,
                       h, ws, (float*)d_out);
}

// Round 12
// 779.006 us; speedup vs baseline: 1.3920x; 1.3920x over previous
//
#include <hip/hip_runtime.h>
#include <stdint.h>

// GRU decoder: 65536 rows, H=256, T=12, D_OUT=64.
// R12 = R10 base (register-state, swapped-operand MFMA, 8 waves x 32 rows,
// 256 blocks = 1/CU) + panels merged 2-per-phase: 102 barriers instead of
// 204. 17 panels/step is odd -> unroll TWO GRU steps per iteration
// (34 panels = 17 pairs exactly); h/hn array roles alternate per step
// (no h<-hn copy). LDS: 2 pair-slots x 64KB ring + 3.3KB biases = 134.4KB.
// vmcnt(0) at pair boundary: staging loads were issued one full phase ago.

#define TSTEPS 12
#define AS3 __attribute__((address_space(3)))

typedef _Float16 f16x8 __attribute__((ext_vector_type(8)));
typedef _Float16 f16x2 __attribute__((ext_vector_type(2)));
typedef float    f32x16 __attribute__((ext_vector_type(16)));
typedef float    f32x4  __attribute__((ext_vector_type(4)));
typedef uint32_t u32x4  __attribute__((ext_vector_type(4)));

typedef AS3 uint8_t       u8l;
typedef const AS3 uint8_t cu8l;

// ws: f16 weights (panels of 64 rows x 256 k = 32KB):
//   0-3 gate-r(folded), 4-7 gate-z(folded), 8-11 W1, 12-15 W2, 16 Wp
// then f32 bias block in C-layout e-pattern order.
#define WG_E (512*256)
#define W1_E (256*256)
#define WS_W_F16 (WG_E + 2*W1_E + 64*256)
#define BIAS_F32 832
#define WS_BYTES (WS_W_F16*2 + BIAS_F32*4)

__global__ void prep_weights(const float* __restrict__ gw,
                             const float* __restrict__ ow,
                             const float* __restrict__ pw,
                             const float* __restrict__ gb,
                             const float* __restrict__ ob,
                             const float* __restrict__ pb,
                             _Float16* __restrict__ ws)
{
    int idx = blockIdx.x*256 + threadIdx.x;
    if (idx < WG_E) {                           // folded gates
        int j = idx >> 8, k = idx & 255;
        ws[idx] = (_Float16)(gw[j*512 + k] + gw[j*512 + 256 + k]);
    } else if (idx < WG_E + W1_E) {             // W1 = out_w[:, :256]
        int i = idx - WG_E; int r = i >> 8, c = i & 255;
        ws[idx] = (_Float16)ow[r*512 + c];
    } else if (idx < WG_E + 2*W1_E) {           // W2 = out_w[:, 256:]
        int i = idx - WG_E - W1_E; int r = i >> 8, c = i & 255;
        ws[idx] = (_Float16)ow[r*512 + 256 + c];
    } else if (idx < WS_W_F16) {                // Wp
        ws[idx] = (_Float16)pw[idx - WG_E - 2*W1_E];
    } else if (idx < WS_W_F16 + BIAS_F32) {     // expanded biases (f32)
        int b = idx - WS_W_F16;
        float* bd = (float*)(ws + WS_W_F16);
        if (b < 768) {
            int type = b >> 8, r = b & 255;
            int c = r >> 6, n = (r >> 5) & 1, kg = (r >> 4) & 1, e = r & 15;
            int col = 64*c + 32*n + 4*kg + (e & 3) + 8*(e >> 2);
            bd[b] = (type == 0) ? gb[col] : (type == 1) ? gb[256 + col] : ob[col];
        } else {
            int i = b - 768;
            int n = (i >> 5) & 1, kg = (i >> 4) & 1, e = i & 15;
            bd[b] = pb[32*n + 4*kg + (e & 3) + 8*(e >> 2)];
        }
    }
}

__device__ __forceinline__ float sigm(float x)  { return 1.0f/(1.0f+__expf(-x)); }
__device__ __forceinline__ float tanh_(float x) { return 1.0f - 2.0f/(1.0f+__expf(2.0f*x)); }

// stage one 32KB panel (8 waves x 4 gll16). LDS dest linear; global source
// pre-applies the inverse chunk-XOR layout permutation.
__device__ __forceinline__ void stage(const uint8_t* __restrict__ Wp,
                                      u8l* slot, int w, int lane)
{
    #pragma unroll
    for (int i = 0; i < 4; ++i) {
        int d  = w*4096 + i*1024;
        int dl = d + lane*16;
        int chunk = (dl>>7)&31, sl = (dl>>4)&7;
        int row = ((dl>>12)<<3) | (sl ^ (chunk&7));
        int s   = row*512 + chunk*16;
        __builtin_amdgcn_global_load_lds(
            (const __attribute__((address_space(1))) uint32_t*)(Wp + s),
            (AS3 uint32_t*)(slot + d), 16, 0, 0);
    }
}

// load f32x16 bias (broadcast within kg-half)
__device__ __forceinline__ f32x16 ldbias(cu8l* p) {
    f32x16 r;
    #pragma unroll
    for (int j = 0; j < 4; ++j) {
        f32x4 t = *(const AS3 f32x4*)(p + j*16);
        r[j*4+0]=t[0]; r[j*4+1]=t[1]; r[j*4+2]=t[2]; r[j*4+3]=t[3];
    }
    return r;
}

// pack 4 f16x2 words (C-layout e-pattern, 8 outcols) -> B-frag f16x8.
__device__ __forceinline__ f16x8 pk8(uint32_t w01, uint32_t w23,
                                     uint32_t w45, uint32_t w67, int kg) {
    uint32_t s01 = __shfl_xor(w01, 32, 64);
    uint32_t s23 = __shfl_xor(w23, 32, 64);
    uint32_t s45 = __shfl_xor(w45, 32, 64);
    uint32_t s67 = __shfl_xor(w67, 32, 64);
    u32x4 u = { kg ? s45 : w01, kg ? s67 : w23,
                kg ? w45 : s01, kg ? w67 : s23 };
    return __builtin_bit_cast(f16x8, u);
}
__device__ __forceinline__ f16x8 pkS(const f32x16& a, int off, int kg) {
    f16x2 a01 = {(_Float16)sigm(a[off+0]), (_Float16)sigm(a[off+1])};
    f16x2 a23 = {(_Float16)sigm(a[off+2]), (_Float16)sigm(a[off+3])};
    f16x2 a45 = {(_Float16)sigm(a[off+4]), (_Float16)sigm(a[off+5])};
    f16x2 a67 = {(_Float16)sigm(a[off+6]), (_Float16)sigm(a[off+7])};
    return pk8(__builtin_bit_cast(uint32_t, a01), __builtin_bit_cast(uint32_t, a23),
               __builtin_bit_cast(uint32_t, a45), __builtin_bit_cast(uint32_t, a67), kg);
}
__device__ __forceinline__ f16x8 pkT(const f32x16& a, int off, int kg) {
    f16x2 a01 = {(_Float16)tanh_(a[off+0]), (_Float16)tanh_(a[off+1])};
    f16x2 a23 = {(_Float16)tanh_(a[off+2]), (_Float16)tanh_(a[off+3])};
    f16x2 a45 = {(_Float16)tanh_(a[off+4]), (_Float16)tanh_(a[off+5])};
    f16x2 a67 = {(_Float16)tanh_(a[off+6]), (_Float16)tanh_(a[off+7])};
    return pk8(__builtin_bit_cast(uint32_t, a01), __builtin_bit_cast(uint32_t, a23),
               __builtin_bit_cast(uint32_t, a45), __builtin_bit_cast(uint32_t, a67), kg);
}

// one panel GEMM: acc_n += W[32n+(l&31), k] * B (B = reg-resident state)
__device__ __forceinline__ void gemm2(cu8l* pan, int R0, int R1,
                                      const f16x8* B, f32x16& a0, f32x16& a1) {
    #pragma unroll
    for (int ks = 0; ks < 16; ++ks) {
        const int xk = ((2*ks)&7) << 4;
        f16x8 w0 = *(const AS3 f16x8*)(pan + ((R0 ^ xk) + ks*256));
        f16x8 w1 = *(const AS3 f16x8*)(pan + ((R1 ^ xk) + ks*256));
        a0 = __builtin_amdgcn_mfma_f32_32x32x16_f16(w0, B[ks], a0, 0, 0, 0);
        a1 = __builtin_amdgcn_mfma_f32_32x32x16_f16(w1, B[ks], a1, 0, 0, 0);
    }
}

// ---- phase bodies (comma-safe: every top-level comma inside parens) ----
#define R_BODY(C, HC)                                                         \
    f32x16 a0 = ldbias(bK + (C)*256);                                         \
    f32x16 a1 = ldbias(bK + (C)*256 + 128);                                   \
    gemm2(pan, R0, R1, HC, a0, a1);                                           \
    rh[4*(C)+0] = pkS(a0, 0, kg)*HC[4*(C)+0];                                 \
    rh[4*(C)+1] = pkS(a0, 8, kg)*HC[4*(C)+1];                                 \
    rh[4*(C)+2] = pkS(a1, 0, kg)*HC[4*(C)+2];                                 \
    rh[4*(C)+3] = pkS(a1, 8, kg)*HC[4*(C)+3];

#define Z_BODY(C, HC)                                                         \
    f32x16 a0 = ldbias(bK + 1024 + (C)*256);                                  \
    f32x16 a1 = ldbias(bK + 1024 + (C)*256 + 128);                            \
    gemm2(pan, R0, R1, HC, a0, a1);                                           \
    zb[0] = pkS(a0, 0, kg);                                                   \
    zb[1] = pkS(a0, 8, kg);                                                   \
    zb[2] = pkS(a1, 0, kg);                                                   \
    zb[3] = pkS(a1, 8, kg);

#define W1_BODY(C, HC)                                                        \
    o0 = ldbias(bK + 2048 + (C)*256);                                         \
    o1 = ldbias(bK + 2048 + (C)*256 + 128);                                   \
    gemm2(pan, R0, R1, HC, o0, o1);

#define W2_BODY(C, HC, HN)                                                    \
    gemm2(pan, R0, R1, rh, o0, o1);                                           \
    f16x8 u0 = pkT(o0, 0, kg);                                                \
    f16x8 u1 = pkT(o0, 8, kg);                                                \
    f16x8 u2 = pkT(o1, 0, kg);                                                \
    f16x8 u3 = pkT(o1, 8, kg);                                                \
    HN[4*(C)+0] = u0 + zb[0]*(HC[4*(C)+0] - u0);                              \
    HN[4*(C)+1] = u1 + zb[1]*(HC[4*(C)+1] - u1);                              \
    HN[4*(C)+2] = u2 + zb[2]*(HC[4*(C)+2] - u2);                              \
    HN[4*(C)+3] = u3 + zb[3]*(HC[4*(C)+3] - u3);

#define PROJ_BODY(HS, T)                                                      \
    f32x16 a0 = ldbias(bK + 3072);                                            \
    f32x16 a1 = ldbias(bK + 3072 + 128);                                      \
    gemm2(pan, R0, R1, HS, a0, a1);                                           \
    {                                                                         \
        float* op = out + (rowg*TSTEPS + (T))*64 + 4*kg;                      \
        _Pragma("unroll")                                                     \
        for (int j = 0; j < 4; ++j) {                                         \
            f32x4 v0 = {a0[4*j], a0[4*j+1], a0[4*j+2], a0[4*j+3]};            \
            f32x4 v1 = {a1[4*j], a1[4*j+1], a1[4*j+2], a1[4*j+3]};            \
            *(f32x4*)(op + 8*j)      = v0;                                    \
            *(f32x4*)(op + 32 + 8*j) = v1;                                    \
        }                                                                     \
    }

// merged phase: wait prev-phase staging -> barrier -> stage next pair ->
// compute both panels of current pair.
#define PH2(SPa, SPb, B0, B1) do {                                           \
    asm volatile("s_waitcnt vmcnt(0)" ::: "memory");                         \
    __builtin_amdgcn_s_barrier();                                            \
    asm volatile("" ::: "memory");                                           \
    stage(W + (SPa)*32768, WbL + (sP^1)*65536,         w, lane);              \
    stage(W + (SPb)*32768, WbL + (sP^1)*65536 + 32768, w, lane);              \
    { cu8l* pan = WbL + sP*65536;         B0 }                                \
    { cu8l* pan = WbL + sP*65536 + 32768; B1 }                                \
    sP ^= 1;                                                                  \
} while (0)

__global__ __launch_bounds__(512, 1)
void gru_dec(const float* __restrict__ h_in, const _Float16* __restrict__ Wf,
             float* __restrict__ out)
{
    __shared__ __align__(16) uint8_t lds_[134400];
    u8l* ldsb = (u8l*)lds_;
    u8l* WbL  = ldsb;                     // 2 x 64KB pair-slot ring
    u8l* biasL = ldsb + 131072;           // 3.3KB expanded biases
    const uint8_t* W = (const uint8_t*)Wf;

    const int tid  = threadIdx.x;
    const int lane = tid & 63;
    const int w    = tid >> 6;            // wave 0..7, owns 32 rows
    const int bl31 = lane & 31;
    const int kg   = lane >> 5;
    const int l7   = lane & 7;
    const size_t rowg = (size_t)blockIdx.x*256 + w*32 + bl31;

    // ---- h -> registers as B-frags: h[ks] = h[rowg, 16ks+8kg+0..7] ----
    f16x8 h[16], rh[16], hn[16];
    {
        const float* hs = h_in + rowg*256 + kg*8;
        #pragma unroll
        for (int ks = 0; ks < 16; ++ks) {
            f32x4 x = *(const f32x4*)(hs + ks*16);
            f32x4 y = *(const f32x4*)(hs + ks*16 + 4);
            f16x8 v = {(_Float16)x[0],(_Float16)x[1],(_Float16)x[2],(_Float16)x[3],
                       (_Float16)y[0],(_Float16)y[1],(_Float16)y[2],(_Float16)y[3]};
            h[ks] = v;
        }
    }
    // ---- biases ws -> LDS ----
    {
        const float* bsrc = (const float*)(Wf + WS_W_F16);
        for (int i = tid; i < BIAS_F32; i += 512)
            *(AS3 float*)(biasL + i*4) = bsrc[i];
    }
    __syncthreads();                      // drains h loads + bias writes

    // per-lane panel-read bases (chunk-XOR layout)
    const int R0 = ((bl31 >> 3))*4096 + kg*128 + ((l7 ^ kg) << 4);
    const int R1 = R0 + 4*4096;
    cu8l* bK = biasL + kg*64;

    stage(W + 0*32768, WbL,         w, lane);   // prologue: pair (r0, r1)
    stage(W + 1*32768, WbL + 32768, w, lane);
    int sP = 0;

    // two GRU steps per iteration: step A uses h -> hn, step B uses hn -> h.
    #pragma unroll 1
    for (int it = 0; it < TSTEPS/2; ++it) {
        const int tA = 2*it, tB = 2*it + 1;
        f32x16 o0, o1;
        f16x8 zb[4];

        // ---- step A (state: h -> hn) ----
        PH2(2, 3,   R_BODY(0, h),        R_BODY(1, h));
        PH2(4, 8,   R_BODY(2, h),        R_BODY(3, h));
        PH2(12, 5,  Z_BODY(0, h),        W1_BODY(0, h));
        PH2(9, 13,  W2_BODY(0, h, hn),   Z_BODY(1, h));
        PH2(6, 10,  W1_BODY(1, h),       W2_BODY(1, h, hn));
        PH2(14, 7,  Z_BODY(2, h),        W1_BODY(2, h));
        PH2(11, 15, W2_BODY(2, h, hn),   Z_BODY(3, h));
        PH2(16, 0,  W1_BODY(3, h),       W2_BODY(3, h, hn));
        // ---- step A proj + step B r0 (state now in hn) ----
        PH2(1, 2,   PROJ_BODY(hn, tA),   R_BODY(0, hn));
        // ---- step B (state: hn -> h) ----
        PH2(3, 4,   R_BODY(1, hn),       R_BODY(2, hn));
        PH2(8, 12,  R_BODY(3, hn),       Z_BODY(0, hn));
        PH2(5, 9,   W1_BODY(0, hn),      W2_BODY(0, hn, h));
        PH2(13, 6,  Z_BODY(1, hn),       W1_BODY(1, hn));
        PH2(10, 14, W2_BODY(1, hn, h),   Z_BODY(2, hn));
        PH2(7, 11,  W1_BODY(2, hn),      W2_BODY(2, hn, h));
        PH2(15, 16, Z_BODY(3, hn),       W1_BODY(3, hn));
        PH2(0, 1,   W2_BODY(3, hn, h),   PROJ_BODY(h, tB));
        // final stage (0,1) feeds next iteration's first phase
    }
    asm volatile("s_waitcnt vmcnt(0)" ::: "memory");  // drain tail staging
}

extern "C" void kernel_launch(void* const* d_in, const int* in_sizes, int n_in,
                              void* d_out, int out_size, void* d_ws, size_t ws_size,
                              hipStream_t stream) {
    // inputs: 0:x(=12) 1:h 2:gate_w 3:gate_b 4:out_w 5:out_b 6:proj_w 7:proj_b
    const float* h  = (const float*)d_in[1];
    const float* gw = (const float*)d_in[2];
    const float* gb = (const float*)d_in[3];
    const float* ow = (const float*)d_in[4];
    const float* ob = (const float*)d_in[5];
    const float* pw = (const float*)d_in[6];
    const float* pb = (const float*)d_in[7];
    if (ws_size < (size_t)WS_BYTES) return;
    _Float16* ws = (_Float16*)d_ws;

    hipLaunchKernelGGL(prep_weights, dim3((WS_W_F16 + BIAS_F32 + 255)/256), dim3(256),
                       0, stream, gw, ow, pw, gb, ob, pb, ws);
    hipLaunchKernelGGL(gru_dec, dim3(65536/256), dim3(512), 0, stream,
                       h, ws, (float*)d_out);
}

// Round 13
// 717.202 us; speedup vs baseline: 1.5120x; 1.0862x over previous
//
#include <hip/hip_runtime.h>
#include <stdint.h>

// GRU decoder: 65536 rows, H=256, T=12, D_OUT=64.
// R13 = R10 base (register-state, swapped-operand MFMA, 8 waves x 32 rows,
// 256 blocks = 1/CU, ring-3 panel stream) + LANE-LINEAR panel layout:
// chunk c = 2*ks+tile (1KB) holds lane l's A-fragment at c*1024 + l*16,
// so every ds_read_b128 is a contiguous 1KB read (conflict-free, 12cy,
// pure immediate offsets). R10's chunk-XOR layout was an 8-way bank
// conflict on EVERY read (page/kg strides 4096/128 are bank-neutral):
// SQ_LDS_BANK_CONFLICT 5.35e7 ~= 1024 cy/phase/CU. Permutation moved to
// stage()'s per-lane global source (gll dest stays linear per HW rule).

#define TSTEPS 12
#define AS3 __attribute__((address_space(3)))

typedef _Float16 f16x8 __attribute__((ext_vector_type(8)));
typedef _Float16 f16x2 __attribute__((ext_vector_type(2)));
typedef float    f32x16 __attribute__((ext_vector_type(16)));
typedef float    f32x4  __attribute__((ext_vector_type(4)));
typedef uint32_t u32x4  __attribute__((ext_vector_type(4)));

typedef AS3 uint8_t       u8l;
typedef const AS3 uint8_t cu8l;

// ws: f16 weights (panels of 64 rows x 256 k = 32KB, row-major):
//   0-3 gate-r(folded), 4-7 gate-z(folded), 8-11 W1, 12-15 W2, 16 Wp
// then f32 bias block in C-layout e-pattern order.
#define WG_E (512*256)
#define W1_E (256*256)
#define WS_W_F16 (WG_E + 2*W1_E + 64*256)
#define BIAS_F32 832
#define WS_BYTES (WS_W_F16*2 + BIAS_F32*4)

__global__ void prep_weights(const float* __restrict__ gw,
                             const float* __restrict__ ow,
                             const float* __restrict__ pw,
                             const float* __restrict__ gb,
                             const float* __restrict__ ob,
                             const float* __restrict__ pb,
                             _Float16* __restrict__ ws)
{
    int idx = blockIdx.x*256 + threadIdx.x;
    if (idx < WG_E) {                           // folded gates
        int j = idx >> 8, k = idx & 255;
        ws[idx] = (_Float16)(gw[j*512 + k] + gw[j*512 + 256 + k]);
    } else if (idx < WG_E + W1_E) {             // W1 = out_w[:, :256]
        int i = idx - WG_E; int r = i >> 8, c = i & 255;
        ws[idx] = (_Float16)ow[r*512 + c];
    } else if (idx < WG_E + 2*W1_E) {           // W2 = out_w[:, 256:]
        int i = idx - WG_E - W1_E; int r = i >> 8, c = i & 255;
        ws[idx] = (_Float16)ow[r*512 + 256 + c];
    } else if (idx < WS_W_F16) {                // Wp
        ws[idx] = (_Float16)pw[idx - WG_E - 2*W1_E];
    } else if (idx < WS_W_F16 + BIAS_F32) {     // expanded biases (f32)
        int b = idx - WS_W_F16;
        float* bd = (float*)(ws + WS_W_F16);
        if (b < 768) {
            int type = b >> 8, r = b & 255;
            int c = r >> 6, n = (r >> 5) & 1, kg = (r >> 4) & 1, e = r & 15;
            int col = 64*c + 32*n + 4*kg + (e & 3) + 8*(e >> 2);
            bd[b] = (type == 0) ? gb[col] : (type == 1) ? gb[256 + col] : ob[col];
        } else {
            int i = b - 768;
            int n = (i >> 5) & 1, kg = (i >> 4) & 1, e = i & 15;
            bd[b] = pb[32*n + 4*kg + (e & 3) + 8*(e >> 2)];
        }
    }
}

__device__ __forceinline__ float sigm(float x)  { return 1.0f/(1.0f+__expf(-x)); }
__device__ __forceinline__ float tanh_(float x) { return 1.0f - 2.0f/(1.0f+__expf(2.0f*x)); }

// stage one 32KB panel (8 waves x 4 gll16) into lane-linear chunk layout:
// dest chunk c = w*4 + i holds (ks=c>>1, tile=c&1); lane l supplies
// W[tile*32 + (l&31)][ks*16 + (l>>5)*8 ..+7] from the row-major panel.
// laneC = (l&31)*512 + (l>>5)*16 precomputed per thread.
__device__ __forceinline__ void stage(const uint8_t* __restrict__ Wp,
                                      u8l* slot, int w, int laneC)
{
    #pragma unroll
    for (int i = 0; i < 4; ++i) {
        int c    = w*4 + i;                   // chunk 0..31 (wave-uniform)
        int ks   = c >> 1, tile = c & 1;
        int s    = laneC + tile*16384 + ks*32;  // per-lane global source
        __builtin_amdgcn_global_load_lds(
            (const __attribute__((address_space(1))) uint32_t*)(Wp + s),
            (AS3 uint32_t*)(slot + w*4096 + i*1024), 16, 0, 0);
    }
}

// load f32x16 bias (broadcast within kg-half)
__device__ __forceinline__ f32x16 ldbias(cu8l* p) {
    f32x16 r;
    #pragma unroll
    for (int j = 0; j < 4; ++j) {
        f32x4 t = *(const AS3 f32x4*)(p + j*16);
        r[j*4+0]=t[0]; r[j*4+1]=t[1]; r[j*4+2]=t[2]; r[j*4+3]=t[3];
    }
    return r;
}

// pack 4 f16x2 words (C-layout e-pattern, 8 outcols) -> B-frag f16x8.
__device__ __forceinline__ f16x8 pk8(uint32_t w01, uint32_t w23,
                                     uint32_t w45, uint32_t w67, int kg) {
    uint32_t s01 = __shfl_xor(w01, 32, 64);
    uint32_t s23 = __shfl_xor(w23, 32, 64);
    uint32_t s45 = __shfl_xor(w45, 32, 64);
    uint32_t s67 = __shfl_xor(w67, 32, 64);
    u32x4 u = { kg ? s45 : w01, kg ? s67 : w23,
                kg ? w45 : s01, kg ? w67 : s23 };
    return __builtin_bit_cast(f16x8, u);
}
__device__ __forceinline__ f16x8 pkS(const f32x16& a, int off, int kg) {
    f16x2 a01 = {(_Float16)sigm(a[off+0]), (_Float16)sigm(a[off+1])};
    f16x2 a23 = {(_Float16)sigm(a[off+2]), (_Float16)sigm(a[off+3])};
    f16x2 a45 = {(_Float16)sigm(a[off+4]), (_Float16)sigm(a[off+5])};
    f16x2 a67 = {(_Float16)sigm(a[off+6]), (_Float16)sigm(a[off+7])};
    return pk8(__builtin_bit_cast(uint32_t, a01), __builtin_bit_cast(uint32_t, a23),
               __builtin_bit_cast(uint32_t, a45), __builtin_bit_cast(uint32_t, a67), kg);
}
__device__ __forceinline__ f16x8 pkT(const f32x16& a, int off, int kg) {
    f16x2 a01 = {(_Float16)tanh_(a[off+0]), (_Float16)tanh_(a[off+1])};
    f16x2 a23 = {(_Float16)tanh_(a[off+2]), (_Float16)tanh_(a[off+3])};
    f16x2 a45 = {(_Float16)tanh_(a[off+4]), (_Float16)tanh_(a[off+5])};
    f16x2 a67 = {(_Float16)tanh_(a[off+6]), (_Float16)tanh_(a[off+7])};
    return pk8(__builtin_bit_cast(uint32_t, a01), __builtin_bit_cast(uint32_t, a23),
               __builtin_bit_cast(uint32_t, a45), __builtin_bit_cast(uint32_t, a67), kg);
}

// one panel GEMM: acc_n += W[32n+(l&31), k] * B. Reads are lane-linear
// contiguous 1KB per instruction: base + lane*16 + imm (2ks+tile)*1024.
__device__ __forceinline__ void gemm2(cu8l* panL, const f16x8* B,
                                      f32x16& a0, f32x16& a1) {
    #pragma unroll
    for (int ks = 0; ks < 16; ++ks) {
        f16x8 w0 = *(const AS3 f16x8*)(panL + ks*2048);
        f16x8 w1 = *(const AS3 f16x8*)(panL + ks*2048 + 1024);
        a0 = __builtin_amdgcn_mfma_f32_32x32x16_f16(w0, B[ks], a0, 0, 0, 0);
        a1 = __builtin_amdgcn_mfma_f32_32x32x16_f16(w1, B[ks], a1, 0, 0, 0);
    }
}

// phase: wait panel (per-wave vmcnt(4): 2 stages of 4 in flight) -> barrier
// -> stage 2-ahead -> compute
#define PHASE(SP, ...) do {                                                 \
    asm volatile("s_waitcnt vmcnt(4)" ::: "memory");                        \
    asm volatile("s_waitcnt lgkmcnt(0)" ::: "memory");                      \
    __builtin_amdgcn_s_barrier();                                           \
    asm volatile("" ::: "memory");                                          \
    stage(W + (SP)*32768, WbL + sS*32768, w, laneC);                        \
    { cu8l* panL = WbL + sC*32768 + LB; __VA_ARGS__; }                      \
    sC = (sC == 2) ? 0 : sC + 1;                                            \
    sS = (sS == 2) ? 0 : sS + 1;                                            \
} while (0)

__global__ __launch_bounds__(512, 1)
void gru_dec(const float* __restrict__ h_in, const _Float16* __restrict__ Wf,
             float* __restrict__ out)
{
    __shared__ __align__(16) uint8_t lds_[101632];
    u8l* ldsb = (u8l*)lds_;
    u8l* WbL  = ldsb;                     // 3 x 32KB panel ring
    u8l* biasL = ldsb + 98304;            // 3.3KB expanded biases
    const uint8_t* W = (const uint8_t*)Wf;

    const int tid  = threadIdx.x;
    const int lane = tid & 63;
    const int w    = tid >> 6;            // wave 0..7, owns 32 rows
    const int bl31 = lane & 31;
    const int kg   = lane >> 5;
    const size_t rowg = (size_t)blockIdx.x*256 + w*32 + bl31;

    const int laneC = bl31*512 + kg*16;   // per-lane stage source constant
    const int LB    = lane*16;            // per-lane ds-read base

    // ---- h -> registers as B-frags: h[ks] = h[rowg, 16ks+8kg+0..7] ----
    f16x8 h[16], rh[16], hn[16];
    {
        const float* hs = h_in + rowg*256 + kg*8;
        #pragma unroll
        for (int ks = 0; ks < 16; ++ks) {
            f32x4 x = *(const f32x4*)(hs + ks*16);
            f32x4 y = *(const f32x4*)(hs + ks*16 + 4);
            f16x8 v = {(_Float16)x[0],(_Float16)x[1],(_Float16)x[2],(_Float16)x[3],
                       (_Float16)y[0],(_Float16)y[1],(_Float16)y[2],(_Float16)y[3]};
            h[ks] = v;
        }
    }
    // ---- biases ws -> LDS ----
    {
        const float* bsrc = (const float*)(Wf + WS_W_F16);
        for (int i = tid; i < BIAS_F32; i += 512)
            *(AS3 float*)(biasL + i*4) = bsrc[i];
    }
    __syncthreads();                      // drains h loads + bias writes

    cu8l* bK = biasL + kg*64;

    stage(W + 0*32768, WbL,         w, laneC);   // prologue: panel r0
    stage(W + 1*32768, WbL + 32768, w, laneC);   // panel r1
    int sC = 0, sS = 2;

    for (int t = 0; t < TSTEPS; ++t) {
        f32x16 o0, o1;
        f16x8 zb[4];

        // ---- r gates (panels 0..3): rh[4c+i] = sigm(h@Wr_c + rb) * h ----
#define RPH(SP_STG, C)                                                        \
        PHASE(SP_STG, {                                                       \
            f32x16 a0 = ldbias(bK + (C)*256);                                 \
            f32x16 a1 = ldbias(bK + (C)*256 + 128);                           \
            gemm2(panL, h, a0, a1);                                           \
            rh[4*(C)+0] = pkS(a0, 0, kg)*h[4*(C)+0];                          \
            rh[4*(C)+1] = pkS(a0, 8, kg)*h[4*(C)+1];                          \
            rh[4*(C)+2] = pkS(a1, 0, kg)*h[4*(C)+2];                          \
            rh[4*(C)+3] = pkS(a1, 8, kg)*h[4*(C)+3]; })
        RPH(2, 0); RPH(3, 1); RPH(4, 2); RPH(8, 3);
#undef RPH

        // ---- per chunk c: z -> W1 -> W2+combine ----
#define ZPH(SP_STG, C)                                                        \
        PHASE(SP_STG, {                                                       \
            f32x16 a0 = ldbias(bK + 1024 + (C)*256);                          \
            f32x16 a1 = ldbias(bK + 1024 + (C)*256 + 128);                    \
            gemm2(panL, h, a0, a1);                                           \
            zb[0] = pkS(a0, 0, kg); zb[1] = pkS(a0, 8, kg);                   \
            zb[2] = pkS(a1, 0, kg); zb[3] = pkS(a1, 8, kg); })
#define W1PH(SP_STG, C)                                                       \
        PHASE(SP_STG, {                                                       \
            o0 = ldbias(bK + 2048 + (C)*256);                                 \
            o1 = ldbias(bK + 2048 + (C)*256 + 128);                           \
            gemm2(panL, h, o0, o1); })
#define W2PH(SP_STG, C)                                                       \
        PHASE(SP_STG, {                                                       \
            gemm2(panL, rh, o0, o1);                                          \
            f16x8 u0 = pkT(o0, 0, kg), u1 = pkT(o0, 8, kg);                   \
            f16x8 u2 = pkT(o1, 0, kg), u3 = pkT(o1, 8, kg);                   \
            hn[4*(C)+0] = u0 + zb[0]*(h[4*(C)+0] - u0);                       \
            hn[4*(C)+1] = u1 + zb[1]*(h[4*(C)+1] - u1);                       \
            hn[4*(C)+2] = u2 + zb[2]*(h[4*(C)+2] - u2);                       \
            hn[4*(C)+3] = u3 + zb[3]*(h[4*(C)+3] - u3); })

        ZPH(12, 0); W1PH(5, 0); W2PH(9,  0);
        ZPH(13, 1); W1PH(6, 1); W2PH(10, 1);
        ZPH(14, 2); W1PH(7, 2); W2PH(11, 2);
        ZPH(15, 3); W1PH(16,3); W2PH(0,  3);
#undef ZPH
#undef W1PH
#undef W2PH

        // h <- h_new
        #pragma unroll
        for (int i = 0; i < 16; ++i) h[i] = hn[i];

        // ---- proj (panel 16): out_t = h_new @ Wp^T + pb ----
        PHASE(1, {
            f32x16 a0 = ldbias(bK + 3072);
            f32x16 a1 = ldbias(bK + 3072 + 128);
            gemm2(panL, h, a0, a1);
            float* op = out + (rowg*TSTEPS + t)*64 + 4*kg;
            _Pragma("unroll")
            for (int j = 0; j < 4; ++j) {
                f32x4 v0 = {a0[4*j], a0[4*j+1], a0[4*j+2], a0[4*j+3]};
                f32x4 v1 = {a1[4*j], a1[4*j+1], a1[4*j+2], a1[4*j+3]};
                *(f32x4*)(op + 8*j)      = v0;
                *(f32x4*)(op + 32 + 8*j) = v1;
            }
        });
    }
}

extern "C" void kernel_launch(void* const* d_in, const int* in_sizes, int n_in,
                              void* d_out, int out_size, void* d_ws, size_t ws_size,
                              hipStream_t stream) {
    // inputs: 0:x(=12) 1:h 2:gate_w 3:gate_b 4:out_w 5:out_b 6:proj_w 7:proj_b
    const float* h  = (const float*)d_in[1];
    const float* gw = (const float*)d_in[2];
    const float* gb = (const float*)d_in[3];
    const float* ow = (const float*)d_in[4];
    const float* ob = (const float*)d_in[5];
    const float* pw = (const float*)d_in[6];
    const float* pb = (const float*)d_in[7];
    if (ws_size < (size_t)WS_BYTES) return;
    _Float16* ws = (_Float16*)d_ws;

    hipLaunchKernelGGL(prep_weights, dim3((WS_W_F16 + BIAS_F32 + 255)/256), dim3(256),
                       0, stream, gw, ow, pw, gb, ob, pb, ws);
    hipLaunchKernelGGL(gru_dec, dim3(65536/256), dim3(512), 0, stream,
                       h, ws, (float*)d_out);
}

// Round 16
// 574.121 us; speedup vs baseline: 1.8888x; 1.2492x over previous
//
#include <hip/hip_runtime.h>
#include <stdint.h>

// GRU decoder: 65536 rows, H=256, T=12, D_OUT=64.
// R16 = R13 (register-state, swapped-operand MFMA, 8 waves x 32 rows,
// 256 blocks = 1/CU, ring-3 lane-linear panel stream, conflict-free)
// + cheap pack path, fully compiler-managed:
//   - sigm/tanh via __builtin_amdgcn_rcpf (not the R14/R15 error source:
//     R15 changed rcp impl, error unchanged)
//   - B-frag repack via __builtin_amdgcn_permlane32_swap BUILTIN. R14/R15's
//     raw asm permlane bypassed the compiler's VALU->permlane hazard nops
//     (INLINEASM is opaque to the hazard recognizer) -> stale reads,
//     absmax 0.06. Builtin lets the compiler insert the wait states.

#define TSTEPS 12
#define AS3 __attribute__((address_space(3)))

typedef _Float16 f16x8 __attribute__((ext_vector_type(8)));
typedef _Float16 f16x2 __attribute__((ext_vector_type(2)));
typedef float    f32x16 __attribute__((ext_vector_type(16)));
typedef float    f32x4  __attribute__((ext_vector_type(4)));
typedef uint32_t u32x4  __attribute__((ext_vector_type(4)));
typedef uint32_t u32x2  __attribute__((ext_vector_type(2)));

typedef AS3 uint8_t       u8l;
typedef const AS3 uint8_t cu8l;

// ws: f16 weights (panels of 64 rows x 256 k = 32KB, row-major):
//   0-3 gate-r(folded), 4-7 gate-z(folded), 8-11 W1, 12-15 W2, 16 Wp
// then f32 bias block in C-layout e-pattern order.
#define WG_E (512*256)
#define W1_E (256*256)
#define WS_W_F16 (WG_E + 2*W1_E + 64*256)
#define BIAS_F32 832
#define WS_BYTES (WS_W_F16*2 + BIAS_F32*4)

__global__ void prep_weights(const float* __restrict__ gw,
                             const float* __restrict__ ow,
                             const float* __restrict__ pw,
                             const float* __restrict__ gb,
                             const float* __restrict__ ob,
                             const float* __restrict__ pb,
                             _Float16* __restrict__ ws)
{
    int idx = blockIdx.x*256 + threadIdx.x;
    if (idx < WG_E) {                           // folded gates
        int j = idx >> 8, k = idx & 255;
        ws[idx] = (_Float16)(gw[j*512 + k] + gw[j*512 + 256 + k]);
    } else if (idx < WG_E + W1_E) {             // W1 = out_w[:, :256]
        int i = idx - WG_E; int r = i >> 8, c = i & 255;
        ws[idx] = (_Float16)ow[r*512 + c];
    } else if (idx < WG_E + 2*W1_E) {           // W2 = out_w[:, 256:]
        int i = idx - WG_E - W1_E; int r = i >> 8, c = i & 255;
        ws[idx] = (_Float16)ow[r*512 + 256 + c];
    } else if (idx < WS_W_F16) {                // Wp
        ws[idx] = (_Float16)pw[idx - WG_E - 2*W1_E];
    } else if (idx < WS_W_F16 + BIAS_F32) {     // expanded biases (f32)
        int b = idx - WS_W_F16;
        float* bd = (float*)(ws + WS_W_F16);
        if (b < 768) {
            int type = b >> 8, r = b & 255;
            int c = r >> 6, n = (r >> 5) & 1, kg = (r >> 4) & 1, e = r & 15;
            int col = 64*c + 32*n + 4*kg + (e & 3) + 8*(e >> 2);
            bd[b] = (type == 0) ? gb[col] : (type == 1) ? gb[256 + col] : ob[col];
        } else {
            int i = b - 768;
            int n = (i >> 5) & 1, kg = (i >> 4) & 1, e = i & 15;
            bd[b] = pb[32*n + 4*kg + (e & 3) + 8*(e >> 2)];
        }
    }
}

__device__ __forceinline__ float sigm(float x) {
    return __builtin_amdgcn_rcpf(1.0f + __expf(-x));
}
__device__ __forceinline__ float tanh_(float x) {
    return 1.0f - 2.0f*__builtin_amdgcn_rcpf(1.0f + __expf(2.0f*x));
}

// stage one 32KB panel (8 waves x 4 gll16) into lane-linear chunk layout:
// dest chunk c = w*4 + i holds (ks=c>>1, tile=c&1); lane l supplies
// W[tile*32 + (l&31)][ks*16 + (l>>5)*8 ..+7] from the row-major panel.
__device__ __forceinline__ void stage(const uint8_t* __restrict__ Wp,
                                      u8l* slot, int w, int laneC)
{
    #pragma unroll
    for (int i = 0; i < 4; ++i) {
        int c    = w*4 + i;                   // chunk 0..31 (wave-uniform)
        int ks   = c >> 1, tile = c & 1;
        int s    = laneC + tile*16384 + ks*32;  // per-lane global source
        __builtin_amdgcn_global_load_lds(
            (const __attribute__((address_space(1))) uint32_t*)(Wp + s),
            (AS3 uint32_t*)(slot + w*4096 + i*1024), 16, 0, 0);
    }
}

// load f32x16 bias (broadcast within kg-half)
__device__ __forceinline__ f32x16 ldbias(cu8l* p) {
    f32x16 r;
    #pragma unroll
    for (int j = 0; j < 4; ++j) {
        f32x4 t = *(const AS3 f32x4*)(p + j*16);
        r[j*4+0]=t[0]; r[j*4+1]=t[1]; r[j*4+2]=t[2]; r[j*4+3]=t[3];
    }
    return r;
}

// C-layout e-pattern (8 outcols) -> B-frag f16x8 via permlane32_swap builtin:
// swap exchanges vdst's upper 32 lanes with vsrc's lower 32 lanes.
//   kg=0 lane: {own a01, own a23, partner a01, partner a23}
//   kg=1 lane: {partner a45, partner a67, own a45, own a67}
// == the shfl_xor(32)+kg-select version, bit-identical.
__device__ __forceinline__ f16x8 pk8(uint32_t w01, uint32_t w23,
                                     uint32_t w45, uint32_t w67) {
    u32x2 p0 = __builtin_amdgcn_permlane32_swap(w01, w45, false, false);
    u32x2 p1 = __builtin_amdgcn_permlane32_swap(w23, w67, false, false);
    u32x4 u = { p0[0], p1[0], p0[1], p1[1] };
    return __builtin_bit_cast(f16x8, u);
}
__device__ __forceinline__ f16x8 pkS(const f32x16& a, int off) {
    f16x2 a01 = {(_Float16)sigm(a[off+0]), (_Float16)sigm(a[off+1])};
    f16x2 a23 = {(_Float16)sigm(a[off+2]), (_Float16)sigm(a[off+3])};
    f16x2 a45 = {(_Float16)sigm(a[off+4]), (_Float16)sigm(a[off+5])};
    f16x2 a67 = {(_Float16)sigm(a[off+6]), (_Float16)sigm(a[off+7])};
    return pk8(__builtin_bit_cast(uint32_t, a01), __builtin_bit_cast(uint32_t, a23),
               __builtin_bit_cast(uint32_t, a45), __builtin_bit_cast(uint32_t, a67));
}
__device__ __forceinline__ f16x8 pkT(const f32x16& a, int off) {
    f16x2 a01 = {(_Float16)tanh_(a[off+0]), (_Float16)tanh_(a[off+1])};
    f16x2 a23 = {(_Float16)tanh_(a[off+2]), (_Float16)tanh_(a[off+3])};
    f16x2 a45 = {(_Float16)tanh_(a[off+4]), (_Float16)tanh_(a[off+5])};
    f16x2 a67 = {(_Float16)tanh_(a[off+6]), (_Float16)tanh_(a[off+7])};
    return pk8(__builtin_bit_cast(uint32_t, a01), __builtin_bit_cast(uint32_t, a23),
               __builtin_bit_cast(uint32_t, a45), __builtin_bit_cast(uint32_t, a67));
}

// one panel GEMM: acc_n += W[32n+(l&31), k] * B. Reads are lane-linear
// contiguous 1KB per instruction: base + lane*16 + imm (2ks+tile)*1024.
__device__ __forceinline__ void gemm2(cu8l* panL, const f16x8* B,
                                      f32x16& a0, f32x16& a1) {
    #pragma unroll
    for (int ks = 0; ks < 16; ++ks) {
        f16x8 w0 = *(const AS3 f16x8*)(panL + ks*2048);
        f16x8 w1 = *(const AS3 f16x8*)(panL + ks*2048 + 1024);
        a0 = __builtin_amdgcn_mfma_f32_32x32x16_f16(w0, B[ks], a0, 0, 0, 0);
        a1 = __builtin_amdgcn_mfma_f32_32x32x16_f16(w1, B[ks], a1, 0, 0, 0);
    }
}

// phase: wait panel (per-wave vmcnt(4): 2 stages of 4 in flight) -> barrier
// -> stage 2-ahead -> compute
#define PHASE(SP, ...) do {                                                 \
    asm volatile("s_waitcnt vmcnt(4)" ::: "memory");                        \
    asm volatile("s_waitcnt lgkmcnt(0)" ::: "memory");                      \
    __builtin_amdgcn_s_barrier();                                           \
    asm volatile("" ::: "memory");                                          \
    stage(W + (SP)*32768, WbL + sS*32768, w, laneC);                        \
    { cu8l* panL = WbL + sC*32768 + LB; __VA_ARGS__; }                      \
    sC = (sC == 2) ? 0 : sC + 1;                                            \
    sS = (sS == 2) ? 0 : sS + 1;                                            \
} while (0)

__global__ __launch_bounds__(512, 1)
void gru_dec(const float* __restrict__ h_in, const _Float16* __restrict__ Wf,
             float* __restrict__ out)
{
    __shared__ __align__(16) uint8_t lds_[101632];
    u8l* ldsb = (u8l*)lds_;
    u8l* WbL  = ldsb;                     // 3 x 32KB panel ring
    u8l* biasL = ldsb + 98304;            // 3.3KB expanded biases
    const uint8_t* W = (const uint8_t*)Wf;

    const int tid  = threadIdx.x;
    const int lane = tid & 63;
    const int w    = tid >> 6;            // wave 0..7, owns 32 rows
    const int bl31 = lane & 31;
    const int kg   = lane >> 5;
    const size_t rowg = (size_t)blockIdx.x*256 + w*32 + bl31;

    const int laneC = bl31*512 + kg*16;   // per-lane stage source constant
    const int LB    = lane*16;            // per-lane ds-read base

    // ---- h -> registers as B-frags: h[ks] = h[rowg, 16ks+8kg+0..7] ----
    f16x8 h[16], rh[16], hn[16];
    {
        const float* hs = h_in + rowg*256 + kg*8;
        #pragma unroll
        for (int ks = 0; ks < 16; ++ks) {
            f32x4 x = *(const f32x4*)(hs + ks*16);
            f32x4 y = *(const f32x4*)(hs + ks*16 + 4);
            f16x8 v = {(_Float16)x[0],(_Float16)x[1],(_Float16)x[2],(_Float16)x[3],
                       (_Float16)y[0],(_Float16)y[1],(_Float16)y[2],(_Float16)y[3]};
            h[ks] = v;
        }
    }
    // ---- biases ws -> LDS ----
    {
        const float* bsrc = (const float*)(Wf + WS_W_F16);
        for (int i = tid; i < BIAS_F32; i += 512)
            *(AS3 float*)(biasL + i*4) = bsrc[i];
    }
    __syncthreads();                      // drains h loads + bias writes

    cu8l* bK = biasL + kg*64;

    stage(W + 0*32768, WbL,         w, laneC);   // prologue: panel r0
    stage(W + 1*32768, WbL + 32768, w, laneC);   // panel r1
    int sC = 0, sS = 2;

    for (int t = 0; t < TSTEPS; ++t) {
        f32x16 o0, o1;
        f16x8 zb[4];

        // ---- r gates (panels 0..3): rh[4c+i] = sigm(h@Wr_c + rb) * h ----
#define RPH(SP_STG, C)                                                        \
        PHASE(SP_STG, {                                                       \
            f32x16 a0 = ldbias(bK + (C)*256);                                 \
            f32x16 a1 = ldbias(bK + (C)*256 + 128);                           \
            gemm2(panL, h, a0, a1);                                           \
            rh[4*(C)+0] = pkS(a0, 0)*h[4*(C)+0];                              \
            rh[4*(C)+1] = pkS(a0, 8)*h[4*(C)+1];                              \
            rh[4*(C)+2] = pkS(a1, 0)*h[4*(C)+2];                              \
            rh[4*(C)+3] = pkS(a1, 8)*h[4*(C)+3]; })
        RPH(2, 0); RPH(3, 1); RPH(4, 2); RPH(8, 3);
#undef RPH

        // ---- per chunk c: z -> W1 -> W2+combine ----
#define ZPH(SP_STG, C)                                                        \
        PHASE(SP_STG, {                                                       \
            f32x16 a0 = ldbias(bK + 1024 + (C)*256);                          \
            f32x16 a1 = ldbias(bK + 1024 + (C)*256 + 128);                    \
            gemm2(panL, h, a0, a1);                                           \
            zb[0] = pkS(a0, 0); zb[1] = pkS(a0, 8);                           \
            zb[2] = pkS(a1, 0); zb[3] = pkS(a1, 8); })
#define W1PH(SP_STG, C)                                                       \
        PHASE(SP_STG, {                                                       \
            o0 = ldbias(bK + 2048 + (C)*256);                                 \
            o1 = ldbias(bK + 2048 + (C)*256 + 128);                           \
            gemm2(panL, h, o0, o1); })
#define W2PH(SP_STG, C)                                                       \
        PHASE(SP_STG, {                                                       \
            gemm2(panL, rh, o0, o1);                                          \
            f16x8 u0 = pkT(o0, 0), u1 = pkT(o0, 8);                           \
            f16x8 u2 = pkT(o1, 0), u3 = pkT(o1, 8);                           \
            hn[4*(C)+0] = u0 + zb[0]*(h[4*(C)+0] - u0);                       \
            hn[4*(C)+1] = u1 + zb[1]*(h[4*(C)+1] - u1);                       \
            hn[4*(C)+2] = u2 + zb[2]*(h[4*(C)+2] - u2);                       \
            hn[4*(C)+3] = u3 + zb[3]*(h[4*(C)+3] - u3); })

        ZPH(12, 0); W1PH(5, 0); W2PH(9,  0);
        ZPH(13, 1); W1PH(6, 1); W2PH(10, 1);
        ZPH(14, 2); W1PH(7, 2); W2PH(11, 2);
        ZPH(15, 3); W1PH(16,3); W2PH(0,  3);
#undef ZPH
#undef W1PH
#undef W2PH

        // h <- h_new
        #pragma unroll
        for (int i = 0; i < 16; ++i) h[i] = hn[i];

        // ---- proj (panel 16): out_t = h_new @ Wp^T + pb ----
        PHASE(1, {
            f32x16 a0 = ldbias(bK + 3072);
            f32x16 a1 = ldbias(bK + 3072 + 128);
            gemm2(panL, h, a0, a1);
            float* op = out + (rowg*TSTEPS + t)*64 + 4*kg;
            _Pragma("unroll")
            for (int j = 0; j < 4; ++j) {
                f32x4 v0 = {a0[4*j], a0[4*j+1], a0[4*j+2], a0[4*j+3]};
                f32x4 v1 = {a1[4*j], a1[4*j+1], a1[4*j+2], a1[4*j+3]};
                *(f32x4*)(op + 8*j)      = v0;
                *(f32x4*)(op + 32 + 8*j) = v1;
            }
        });
    }
}

extern "C" void kernel_launch(void* const* d_in, const int* in_sizes, int n_in,
                              void* d_out, int out_size, void* d_ws, size_t ws_size,
                              hipStream_t stream) {
    // inputs: 0:x(=12) 1:h 2:gate_w 3:gate_b 4:out_w 5:out_b 6:proj_w 7:proj_b
    const float* h  = (const float*)d_in[1];
    const float* gw = (const float*)d_in[2];
    const float* gb = (const float*)d_in[3];
    const float* ow = (const float*)d_in[4];
    const float* ob = (const float*)d_in[5];
    const float* pw = (const float*)d_in[6];
    const float* pb = (const float*)d_in[7];
    if (ws_size < (size_t)WS_BYTES) return;
    _Float16* ws = (_Float16*)d_ws;

    hipLaunchKernelGGL(prep_weights, dim3((WS_W_F16 + BIAS_F32 + 255)/256), dim3(256),
                       0, stream, gw, ow, pw, gb, ob, pb, ws);
    hipLaunchKernelGGL(gru_dec, dim3(65536/256), dim3(512), 0, stream,
                       h, ws, (float*)d_out);
}